// Round 8
// baseline (233.617 us; speedup 1.0000x reference)
//
#include <hip/hip_runtime.h>

#define N_NODES 50000
#define N_EDGES 800000
// D_S=64, D_R=16, D_E=64, D_X=16, D_P=64, NUM_CLASSES=10
// W_r: [144,64]; W_o: [144,64]; W_s: [64,10] (all row-major)
//
// Linear refactor: scores[n] = u0[n] + deg_n*u1[n]
//                              + sum_{e->n} ( u_s[s_e] + R_a[e]@A_R )
//   u_s[n] = O[n]@A_S ; u0[n] = O[n]@A_O + X[n]@A_X + c1 ; u1[n] = O[n]@A_dO + c0
// with Wc = W_o@W_s [144,10], Wc2 = Wc[80:144],
//   A_O = Wc[0:64], A_X = Wc[64:80], A_S = W_r[0:64]@Wc2,
//   A_R = W_r[128:144]@Wc2, A_dO = W_r[64:128]@Wc2,
//   c0 = b_r@Wc2, c1 = b_o@W_s + b_s.
//
// No per-edge intermediate is materialized: the edge term is computed inside
// node_score from a receiver-sorted (edge,sender) int2 list — the only
// scattered write in the whole pipeline is 8 B/edge.
//
// A-table layout in ws: [226][16] f32 (cols 10..15 zeroed):
//   rows 0..63 A_O | 64..79 A_X | 80..143 A_S | 144..159 A_R |
//   160..223 A_dO | 224 c0 | 225 c1

// ---------------------------------------------------------------------------
// Workspace layout (bytes) — total ~13.7 MB (< 26.4 MB proven)
// ---------------------------------------------------------------------------
#define WS_A       ((size_t)0x000000)   // 226*16*4 = 14,464 B
#define WS_COUNT   ((size_t)0x010000)   // 50000 i32 = 200,000 B
#define WS_CURSOR  (WS_COUNT + (size_t)200000)  // 1 u32 (zeroed with count)
#define WS_OFF     ((size_t)0x050000)   // 50000 i32
#define WS_CUR     ((size_t)0x090000)   // 50000 i32
#define WS_US      ((size_t)0x0D0000)   // 50000*12 f32 = 2.4 MB (48B rows, f4-aligned)
#define WS_U01     ((size_t)0x320000)   // 50000*20 f32 = 4.0 MB (u0 c0..9 | u1 c0..9)
#define WS_SCAT    ((size_t)0x700000)   // 800000 int2 = 6.4 MB

// ---------------------------------------------------------------------------
// Precompute folded weight table A — 10 blocks, redundant Wc2 in LDS
// ---------------------------------------------------------------------------
__global__ __launch_bounds__(256) void precompute_A(
    const float* __restrict__ W_r, const float* __restrict__ b_r,
    const float* __restrict__ W_o, const float* __restrict__ b_o,
    const float* __restrict__ W_s, const float* __restrict__ b_s,
    float* __restrict__ A)
{
    __shared__ float Wc2[640];  // Wc rows 80..143 (64 x 10)
    const int t = threadIdx.x;

    for (int idx = t; idx < 640; idx += 256) {
        const int row = 80 + idx / 10, c = idx % 10;
        float acc = 0.f;
        for (int j = 0; j < 64; ++j)
            acc = fmaf(W_o[row * 64 + j], W_s[j * 10 + c], acc);
        Wc2[idx] = acc;
    }
    __syncthreads();

    // work items: [0,1356) zero pads | [1356,2156) A_O/A_X | [2156,3596) A_S/A_R/A_dO
    //             [3596,3606) c0 | [3606,3616) c1
    for (int g = blockIdx.x * 256 + t; g < 3616; g += gridDim.x * 256) {
        if (g < 1356) {
            const int row = g / 6, c = 10 + g % 6;
            A[row * 16 + c] = 0.f;
        } else if (g < 2156) {
            const int i = g - 1356, row = i / 10, c = i % 10;
            float acc = 0.f;
            for (int j = 0; j < 64; ++j)
                acc = fmaf(W_o[row * 64 + j], W_s[j * 10 + c], acc);
            A[row * 16 + c] = acc;
        } else if (g < 3596) {
            const int i = g - 2156, k = i / 10, c = i % 10;
            const int wrow = (k < 64) ? k : (k < 80 ? 128 + (k - 64) : 64 + (k - 80));
            const int arow = (k < 64) ? 80 + k : (k < 80 ? 144 + (k - 64) : 160 + (k - 80));
            const float* src = W_r + (size_t)wrow * 64;
            float acc = 0.f;
            for (int m = 0; m < 64; ++m)
                acc = fmaf(src[m], Wc2[m * 10 + c], acc);
            A[arow * 16 + c] = acc;
        } else if (g < 3606) {
            const int c = g - 3596;
            float acc = 0.f;
            for (int m = 0; m < 64; ++m)
                acc = fmaf(b_r[m], Wc2[m * 10 + c], acc);
            A[224 * 16 + c] = acc;
        } else {
            const int c = g - 3606;
            float acc = b_s[c];
            for (int j = 0; j < 64; ++j)
                acc = fmaf(b_o[j], W_s[j * 10 + c], acc);
            A[225 * 16 + c] = acc;
        }
    }
}

// ---------------------------------------------------------------------------
// Per-node 10-vectors: u_s = O@A_S; u0 = O@A_O + X@A_X + c1; u1 = O@A_dO + c0
// Thread = (node, class): tid = n*10 + c — no idle lanes.
// ---------------------------------------------------------------------------
__global__ __launch_bounds__(256) void node_u_kernel(
    const float* __restrict__ O, const float* __restrict__ X,
    const float* __restrict__ A,
    float* __restrict__ us, float* __restrict__ u01)
{
    const int tid = blockIdx.x * 256 + threadIdx.x;
    if (tid >= N_NODES * 10) return;
    const int n = tid / 10;
    const int c = tid - n * 10;

    float vs = 0.f, v0 = 0.f, v1 = 0.f;
    const float* Orow = O + (size_t)n * 64;
#pragma unroll 8
    for (int k = 0; k < 64; ++k) {
        const float o = Orow[k];
        vs = fmaf(o, A[(size_t)(80 + k) * 16 + c], vs);
        v0 = fmaf(o, A[(size_t)k * 16 + c], v0);
        v1 = fmaf(o, A[(size_t)(160 + k) * 16 + c], v1);
    }
    const float* Xrow = X + (size_t)n * 16;
#pragma unroll
    for (int k = 0; k < 16; ++k)
        v0 = fmaf(Xrow[k], A[(size_t)(64 + k) * 16 + c], v0);

    us[(size_t)n * 12 + c] = vs;
    u01[(size_t)n * 20 + c]      = v0 + A[225 * 16 + c];  // + c1
    u01[(size_t)n * 20 + 10 + c] = v1 + A[224 * 16 + c];  // + c0
}

// ---------------------------------------------------------------------------
// Receiver histogram, 4 edges/thread (int4 loads)
// ---------------------------------------------------------------------------
__global__ __launch_bounds__(256) void count_kernel(
    const int* __restrict__ receivers, int* __restrict__ count)
{
    const int t = blockIdx.x * 256 + threadIdx.x;
    if (t * 4 >= N_EDGES) return;
    const int4 r4 = reinterpret_cast<const int4*>(receivers)[t];
    atomicAdd(count + r4.x, 1);
    atomicAdd(count + r4.y, 1);
    atomicAdd(count + r4.z, 1);
    atomicAdd(count + r4.w, 1);
}

// ---------------------------------------------------------------------------
// Segment allocation, wave-aggregated: shfl prefix-sum, 1 atomic per wave.
// ---------------------------------------------------------------------------
__global__ __launch_bounds__(256) void alloc_kernel(
    const int* __restrict__ count, unsigned int* __restrict__ cursor,
    int* __restrict__ off, int* __restrict__ cur)
{
    const int n = blockIdx.x * 256 + threadIdx.x;
    const int lane = threadIdx.x & 63;
    const int c = (n < N_NODES) ? count[n] : 0;

    // inclusive wave scan of c
    int pre = c;
#pragma unroll
    for (int d = 1; d < 64; d <<= 1) {
        const int v = __shfl_up(pre, d);
        if (lane >= d) pre += v;
    }
    const int total = __shfl(pre, 63);
    int base = 0;
    if (lane == 63) base = (int)atomicAdd(cursor, (unsigned int)total);
    base = __shfl(base, 63);

    if (n < N_NODES) {
        const int pos = base + pre - c;  // exclusive prefix
        off[n] = pos;
        cur[n] = pos;
    }
}

// ---------------------------------------------------------------------------
// Scatter (edge, sender) into receiver-sorted slots — 8 B/edge, the only
// scattered write in the pipeline.
// ---------------------------------------------------------------------------
__global__ __launch_bounds__(256) void place_kernel(
    const int* __restrict__ senders, const int* __restrict__ receivers,
    int* __restrict__ cur, int2* __restrict__ scat)
{
    const int e = blockIdx.x * 256 + threadIdx.x;
    if (e >= N_EDGES) return;
    const int r = receivers[e];
    const int s = senders[e];
    const int pos = atomicAdd(cur + r, 1);
    scat[pos] = make_int2(e, s);
}

// ---------------------------------------------------------------------------
// Node scores: thread = (node, class-slot c<16). Edge term computed in-loop:
// R_a row gathered once (full 64B line), u_s from L2-resident table, A_R
// column held in 16 registers. 16-lane-group softmax.
// ---------------------------------------------------------------------------
__global__ __launch_bounds__(256) void node_score_kernel(
    const float* __restrict__ R_a,
    const float* __restrict__ us, const float* __restrict__ u01,
    const int* __restrict__ off, const int* __restrict__ count,
    const int2* __restrict__ scat,
    const float* __restrict__ A,
    float* __restrict__ out)
{
    const int tid = blockIdx.x * 256 + threadIdx.x;
    const int n = tid >> 4;
    const int c = tid & 15;
    if (n >= N_NODES) return;

    const int cc = (c < 10) ? c : 0;  // safe column for idle lanes

    // A_R column c in registers (L1-resident table, 16 scalar loads once)
    float arc[16];
#pragma unroll
    for (int k = 0; k < 16; ++k) arc[k] = A[(size_t)(144 + k) * 16 + cc];

    const int beg = off[n];
    const int dge = count[n];
    const int end = beg + dge;
    float sc = u01[(size_t)n * 20 + cc] + (float)dge * u01[(size_t)n * 20 + 10 + cc];

    int i = beg;
    for (; i + 1 < end; i += 2) {
        const int2 es0 = scat[i];
        const int2 es1 = scat[i + 1];
        const float4* R0 = reinterpret_cast<const float4*>(R_a + (size_t)es0.x * 16);
        const float4* R1 = reinterpret_cast<const float4*>(R_a + (size_t)es1.x * 16);
        const float4 p0 = R0[0], p1 = R0[1], p2 = R0[2], p3 = R0[3];
        const float4 q0 = R1[0], q1 = R1[1], q2 = R1[2], q3 = R1[3];
        sc += us[(size_t)es0.y * 12 + cc];
        sc += us[(size_t)es1.y * 12 + cc];
        sc = fmaf(p0.x, arc[0], sc);  sc = fmaf(q0.x, arc[0], sc);
        sc = fmaf(p0.y, arc[1], sc);  sc = fmaf(q0.y, arc[1], sc);
        sc = fmaf(p0.z, arc[2], sc);  sc = fmaf(q0.z, arc[2], sc);
        sc = fmaf(p0.w, arc[3], sc);  sc = fmaf(q0.w, arc[3], sc);
        sc = fmaf(p1.x, arc[4], sc);  sc = fmaf(q1.x, arc[4], sc);
        sc = fmaf(p1.y, arc[5], sc);  sc = fmaf(q1.y, arc[5], sc);
        sc = fmaf(p1.z, arc[6], sc);  sc = fmaf(q1.z, arc[6], sc);
        sc = fmaf(p1.w, arc[7], sc);  sc = fmaf(q1.w, arc[7], sc);
        sc = fmaf(p2.x, arc[8], sc);  sc = fmaf(q2.x, arc[8], sc);
        sc = fmaf(p2.y, arc[9], sc);  sc = fmaf(q2.y, arc[9], sc);
        sc = fmaf(p2.z, arc[10], sc); sc = fmaf(q2.z, arc[10], sc);
        sc = fmaf(p2.w, arc[11], sc); sc = fmaf(q2.w, arc[11], sc);
        sc = fmaf(p3.x, arc[12], sc); sc = fmaf(q3.x, arc[12], sc);
        sc = fmaf(p3.y, arc[13], sc); sc = fmaf(q3.y, arc[13], sc);
        sc = fmaf(p3.z, arc[14], sc); sc = fmaf(q3.z, arc[14], sc);
        sc = fmaf(p3.w, arc[15], sc); sc = fmaf(q3.w, arc[15], sc);
    }
    if (i < end) {
        const int2 es0 = scat[i];
        const float4* R0 = reinterpret_cast<const float4*>(R_a + (size_t)es0.x * 16);
        const float4 p0 = R0[0], p1 = R0[1], p2 = R0[2], p3 = R0[3];
        sc += us[(size_t)es0.y * 12 + cc];
        sc = fmaf(p0.x, arc[0], sc);
        sc = fmaf(p0.y, arc[1], sc);
        sc = fmaf(p0.z, arc[2], sc);
        sc = fmaf(p0.w, arc[3], sc);
        sc = fmaf(p1.x, arc[4], sc);
        sc = fmaf(p1.y, arc[5], sc);
        sc = fmaf(p1.z, arc[6], sc);
        sc = fmaf(p1.w, arc[7], sc);
        sc = fmaf(p2.x, arc[8], sc);
        sc = fmaf(p2.y, arc[9], sc);
        sc = fmaf(p2.z, arc[10], sc);
        sc = fmaf(p2.w, arc[11], sc);
        sc = fmaf(p3.x, arc[12], sc);
        sc = fmaf(p3.y, arc[13], sc);
        sc = fmaf(p3.z, arc[14], sc);
        sc = fmaf(p3.w, arc[15], sc);
    }

    // softmax over the 10 active lanes of this 16-lane group
    float m = (c < 10) ? sc : -3.0e38f;
#pragma unroll
    for (int d = 1; d < 16; d <<= 1) m = fmaxf(m, __shfl_xor(m, d, 16));
    const float ex = (c < 10) ? __expf(sc - m) : 0.f;
    float sum = ex;
#pragma unroll
    for (int d = 1; d < 16; d <<= 1) sum += __shfl_xor(sum, d, 16);
    if (c < 10) out[(size_t)n * 10 + c] = ex / sum;
}

extern "C" void kernel_launch(void* const* d_in, const int* in_sizes, int n_in,
                              void* d_out, int out_size, void* d_ws, size_t ws_size,
                              hipStream_t stream)
{
    const float* O    = (const float*)d_in[0];
    const float* X    = (const float*)d_in[1];
    const float* R_a  = (const float*)d_in[2];
    const int* senders   = (const int*)d_in[3];
    const int* receivers = (const int*)d_in[4];
    const float* W_r  = (const float*)d_in[5];
    const float* b_r  = (const float*)d_in[6];
    const float* W_o  = (const float*)d_in[7];
    const float* b_o  = (const float*)d_in[8];
    const float* W_s  = (const float*)d_in[9];
    const float* b_s  = (const float*)d_in[10];
    float* out = (float*)d_out;
    char* ws = (char*)d_ws;

    float* A      = (float*)(ws + WS_A);
    int* count    = (int*)(ws + WS_COUNT);
    unsigned int* cursor = (unsigned int*)(ws + WS_CURSOR);
    int* off      = (int*)(ws + WS_OFF);
    int* cur      = (int*)(ws + WS_CUR);
    float* us     = (float*)(ws + WS_US);
    float* u01    = (float*)(ws + WS_U01);
    int2* scat    = (int2*)(ws + WS_SCAT);

    // zero count histogram + cursor (adjacent) in one memset
    hipMemsetAsync(count, 0, (size_t)200004, stream);

    precompute_A<<<10, 256, 0, stream>>>(W_r, b_r, W_o, b_o, W_s, b_s, A);

    count_kernel<<<(N_EDGES / 4 + 255) / 256, 256, 0, stream>>>(receivers, count);

    alloc_kernel<<<(N_NODES + 255) / 256, 256, 0, stream>>>(count, cursor, off, cur);

    node_u_kernel<<<(N_NODES * 10 + 255) / 256, 256, 0, stream>>>(O, X, A, us, u01);

    place_kernel<<<(N_EDGES + 255) / 256, 256, 0, stream>>>(senders, receivers, cur, scat);

    node_score_kernel<<<(N_NODES * 16 + 255) / 256, 256, 0, stream>>>(
        R_a, us, u01, off, count, scat, A, out);
}

// Round 9
// 183.369 us; speedup vs baseline: 1.2740x; 1.2740x over previous
//
#include <hip/hip_runtime.h>

#define N_NODES 50000
#define N_EDGES 800000
// D_S=64, D_R=16, D_E=64, D_X=16, D_P=64, NUM_CLASSES=10
// W_r: [144,64]; W_o: [144,64]; W_s: [64,10] (all row-major)
//
// Linear refactor: scores[n] = u0[n] + deg_n*u1[n] + sum_{e->n} w_e
//   w_e  = u_s[s_e] + R_a[e]@A_R          (computed in EDGE order, streamed)
//   u_s[n] = O[n]@A_S ; u0[n] = O[n]@A_O + X[n]@A_X + c1 ; u1[n] = O[n]@A_dO + c0
// with Wc = W_o@W_s [144,10], Wc2 = Wc[80:144],
//   A_O = Wc[0:64], A_X = Wc[64:80], A_S = W_r[0:64]@Wc2,
//   A_R = W_r[128:144]@Wc2, A_dO = W_r[64:128]@Wc2,
//   c0 = b_r@Wc2, c1 = b_o@W_s + b_s.
//
// Data-motion policy (lessons r6/r8): stream big arrays in natural order;
// random-gather only small L2-resident tables; the only scattered WRITE is
// 4 B/edge (perm). w5 (16 MB) is written contiguously in edge order and
// gathered by perm in node_score (reads have no RMW amplification).
//
// A-table layout in ws: [226][16] f32 (cols 10..15 zeroed):
//   rows 0..63 A_O | 64..79 A_X | 80..143 A_S | 144..159 A_R |
//   160..223 A_dO | 224 c0 | 225 c1

// ---------------------------------------------------------------------------
// Workspace layout (bytes) — end = 26,220,544 < 26,414,400 (proven in r3)
// ---------------------------------------------------------------------------
#define WS_A       ((size_t)0)          // 14,464 B
#define WS_COUNT   ((size_t)16384)      // 50000 i32 = 200,000 B
#define WS_CURSOR  ((size_t)216384)     // 1 u32 (zeroed with count memset)
#define WS_OFF     ((size_t)217088)     // 50000 i32
#define WS_CUR     ((size_t)417792)     // 50000 i32
#define WS_US      ((size_t)618496)     // 50000*12 f32 = 2,400,000 B
#define WS_U01     ((size_t)3018752)    // 50000*20 f32 = 4,000,000 B
#define WS_PERM    ((size_t)7019520)    // 800000 i32 = 3,200,000 B (stores e*5)
#define WS_W5      ((size_t)10220544)   // 800000*5 u32 = 16,000,000 B

__device__ __forceinline__ unsigned int f32_to_bf16_rne(float f) {
    unsigned int x = __float_as_uint(f);
    return (x + 0x7fffu + ((x >> 16) & 1u)) >> 16;
}

// ---------------------------------------------------------------------------
// Precompute folded weight table A — 10 blocks, redundant Wc2 in LDS
// ---------------------------------------------------------------------------
__global__ __launch_bounds__(256) void precompute_A(
    const float* __restrict__ W_r, const float* __restrict__ b_r,
    const float* __restrict__ W_o, const float* __restrict__ b_o,
    const float* __restrict__ W_s, const float* __restrict__ b_s,
    float* __restrict__ A)
{
    __shared__ float Wc2[640];  // Wc rows 80..143 (64 x 10)
    const int t = threadIdx.x;

    for (int idx = t; idx < 640; idx += 256) {
        const int row = 80 + idx / 10, c = idx % 10;
        float acc = 0.f;
        for (int j = 0; j < 64; ++j)
            acc = fmaf(W_o[row * 64 + j], W_s[j * 10 + c], acc);
        Wc2[idx] = acc;
    }
    __syncthreads();

    // work items: [0,1356) zero pads | [1356,2156) A_O/A_X | [2156,3596) A_S/A_R/A_dO
    //             [3596,3606) c0 | [3606,3616) c1
    for (int g = blockIdx.x * 256 + t; g < 3616; g += gridDim.x * 256) {
        if (g < 1356) {
            const int row = g / 6, c = 10 + g % 6;
            A[row * 16 + c] = 0.f;
        } else if (g < 2156) {
            const int i = g - 1356, row = i / 10, c = i % 10;
            float acc = 0.f;
            for (int j = 0; j < 64; ++j)
                acc = fmaf(W_o[row * 64 + j], W_s[j * 10 + c], acc);
            A[row * 16 + c] = acc;
        } else if (g < 3596) {
            const int i = g - 2156, k = i / 10, c = i % 10;
            const int wrow = (k < 64) ? k : (k < 80 ? 128 + (k - 64) : 64 + (k - 80));
            const int arow = (k < 64) ? 80 + k : (k < 80 ? 144 + (k - 64) : 160 + (k - 80));
            const float* src = W_r + (size_t)wrow * 64;
            float acc = 0.f;
            for (int m = 0; m < 64; ++m)
                acc = fmaf(src[m], Wc2[m * 10 + c], acc);
            A[arow * 16 + c] = acc;
        } else if (g < 3606) {
            const int c = g - 3596;
            float acc = 0.f;
            for (int m = 0; m < 64; ++m)
                acc = fmaf(b_r[m], Wc2[m * 10 + c], acc);
            A[224 * 16 + c] = acc;
        } else {
            const int c = g - 3606;
            float acc = b_s[c];
            for (int j = 0; j < 64; ++j)
                acc = fmaf(b_o[j], W_s[j * 10 + c], acc);
            A[225 * 16 + c] = acc;
        }
    }
}

// ---------------------------------------------------------------------------
// Per-node 10-vectors: u_s = O@A_S; u0 = O@A_O + X@A_X + c1; u1 = O@A_dO + c0
// ---------------------------------------------------------------------------
__global__ __launch_bounds__(256) void node_u_kernel(
    const float* __restrict__ O, const float* __restrict__ X,
    const float* __restrict__ A,
    float* __restrict__ us, float* __restrict__ u01)
{
    const int tid = blockIdx.x * 256 + threadIdx.x;
    if (tid >= N_NODES * 10) return;
    const int n = tid / 10;
    const int c = tid - n * 10;

    float vs = 0.f, v0 = 0.f, v1 = 0.f;
    const float* Orow = O + (size_t)n * 64;
#pragma unroll 8
    for (int k = 0; k < 64; ++k) {
        const float o = Orow[k];
        vs = fmaf(o, A[(size_t)(80 + k) * 16 + c], vs);
        v0 = fmaf(o, A[(size_t)k * 16 + c], v0);
        v1 = fmaf(o, A[(size_t)(160 + k) * 16 + c], v1);
    }
    const float* Xrow = X + (size_t)n * 16;
#pragma unroll
    for (int k = 0; k < 16; ++k)
        v0 = fmaf(Xrow[k], A[(size_t)(64 + k) * 16 + c], v0);

    us[(size_t)n * 12 + c] = vs;
    u01[(size_t)n * 20 + c]      = v0 + A[225 * 16 + c];  // + c1
    u01[(size_t)n * 20 + 10 + c] = v1 + A[224 * 16 + c];  // + c0
}

// ---------------------------------------------------------------------------
// Receiver histogram, 4 edges/thread (int4 loads)
// ---------------------------------------------------------------------------
__global__ __launch_bounds__(256) void count_kernel(
    const int* __restrict__ receivers, int* __restrict__ count)
{
    const int t = blockIdx.x * 256 + threadIdx.x;
    if (t * 4 >= N_EDGES) return;
    const int4 r4 = reinterpret_cast<const int4*>(receivers)[t];
    atomicAdd(count + r4.x, 1);
    atomicAdd(count + r4.y, 1);
    atomicAdd(count + r4.z, 1);
    atomicAdd(count + r4.w, 1);
}

// ---------------------------------------------------------------------------
// Segment allocation, wave-aggregated: shfl prefix-sum, 1 atomic per wave.
// ---------------------------------------------------------------------------
__global__ __launch_bounds__(256) void alloc_kernel(
    const int* __restrict__ count, unsigned int* __restrict__ cursor,
    int* __restrict__ off, int* __restrict__ cur)
{
    const int n = blockIdx.x * 256 + threadIdx.x;
    const int lane = threadIdx.x & 63;
    const int c = (n < N_NODES) ? count[n] : 0;

    int pre = c;
#pragma unroll
    for (int d = 1; d < 64; d <<= 1) {
        const int v = __shfl_up(pre, d);
        if (lane >= d) pre += v;
    }
    const int total = __shfl(pre, 63);
    int base = 0;
    if (lane == 63) base = (int)atomicAdd(cursor, (unsigned int)total);
    base = __shfl(base, 63);

    if (n < N_NODES) {
        const int pos = base + pre - c;  // exclusive prefix
        off[n] = pos;
        cur[n] = pos;
    }
}

// ---------------------------------------------------------------------------
// Per-edge w_e = u_s[s_e] + R_a[e]@A_R -> bf16-packed w5[e] (CONTIGUOUS,
// edge order). Fused place: perm[pos] = e*5 (4 B scatter — the only one).
// ---------------------------------------------------------------------------
__global__ __launch_bounds__(256) void edge_w_kernel(
    const float* __restrict__ R_a,
    const int* __restrict__ senders, const int* __restrict__ receivers,
    const float* __restrict__ us, const float* __restrict__ A,
    int* __restrict__ cur,
    int* __restrict__ perm,
    unsigned int* __restrict__ w5)   // [E][5] dwords, edge-order
{
    const int e = blockIdx.x * blockDim.x + threadIdx.x;
    if (e >= N_EDGES) return;
    const int s = senders[e];
    const int r = receivers[e];

    // claim sorted slot early — atomic+scatter latency hides under the math
    const int pos = atomicAdd(cur + r, 1);
    perm[pos] = e * 5;

    // u_s[s]: 48 B gather from L2-resident 2.4 MB table
    const float4* U = reinterpret_cast<const float4*>(us + (size_t)s * 12);
    const float4 ua = U[0];
    const float4 ub = U[1];
    const float4 uc = U[2];
    float a[10] = {ua.x, ua.y, ua.z, ua.w, ub.x, ub.y, ub.z, ub.w, uc.x, uc.y};

    // R_a[e] @ A_R (A rows 144..159) — R_a streamed coalesced
    const float4* Rv = reinterpret_cast<const float4*>(R_a + (size_t)e * 16);
#pragma unroll
    for (int kc = 0; kc < 4; ++kc) {
        const float4 b4 = Rv[kc];
        const float* A0 = A + (size_t)(144 + kc * 4) * 16;
#pragma unroll
        for (int c = 0; c < 10; ++c) a[c] = fmaf(b4.x, A0[c], a[c]);
#pragma unroll
        for (int c = 0; c < 10; ++c) a[c] = fmaf(b4.y, A0[16 + c], a[c]);
#pragma unroll
        for (int c = 0; c < 10; ++c) a[c] = fmaf(b4.z, A0[32 + c], a[c]);
#pragma unroll
        for (int c = 0; c < 10; ++c) a[c] = fmaf(b4.w, A0[48 + c], a[c]);
    }

    unsigned int* wp = w5 + (size_t)e * 5;
    wp[0] = f32_to_bf16_rne(a[0]) | (f32_to_bf16_rne(a[1]) << 16);
    wp[1] = f32_to_bf16_rne(a[2]) | (f32_to_bf16_rne(a[3]) << 16);
    wp[2] = f32_to_bf16_rne(a[4]) | (f32_to_bf16_rne(a[5]) << 16);
    wp[3] = f32_to_bf16_rne(a[6]) | (f32_to_bf16_rne(a[7]) << 16);
    wp[4] = f32_to_bf16_rne(a[8]) | (f32_to_bf16_rne(a[9]) << 16);
}

// ---------------------------------------------------------------------------
// Node scores: thread = (node, class-slot c<16). Segment loop: perm
// contiguous, w5 gathered (20 B rows, random within 16 MB L2/L3-resident).
// 4-deep unroll with 4 accumulators for MLP. 16-lane-group softmax.
// ---------------------------------------------------------------------------
__global__ __launch_bounds__(256) void node_score_kernel(
    const float* __restrict__ u01,
    const int* __restrict__ off, const int* __restrict__ count,
    const int* __restrict__ perm,
    const unsigned int* __restrict__ w5,
    float* __restrict__ out)
{
    const int tid = blockIdx.x * 256 + threadIdx.x;
    const int n = tid >> 4;
    const int c = tid & 15;
    if (n >= N_NODES) return;

    const int cc = (c < 10) ? c : 0;  // safe column for idle lanes
    const int half = cc >> 1;
    const int sh = (cc & 1) * 16;

    const int beg = off[n];
    const int dge = count[n];
    const int end = beg + dge;
    float sc = u01[(size_t)n * 20 + cc] + (float)dge * u01[(size_t)n * 20 + 10 + cc];

    float s0 = 0.f, s1 = 0.f, s2 = 0.f, s3 = 0.f;
    int i = beg;
    for (; i + 3 < end; i += 4) {
        const int p0 = perm[i], p1 = perm[i + 1], p2 = perm[i + 2], p3 = perm[i + 3];
        const unsigned int v0 = w5[(size_t)p0 + half];
        const unsigned int v1 = w5[(size_t)p1 + half];
        const unsigned int v2 = w5[(size_t)p2 + half];
        const unsigned int v3 = w5[(size_t)p3 + half];
        s0 += __uint_as_float((v0 >> sh) << 16);
        s1 += __uint_as_float((v1 >> sh) << 16);
        s2 += __uint_as_float((v2 >> sh) << 16);
        s3 += __uint_as_float((v3 >> sh) << 16);
    }
    for (; i < end; ++i) {
        const unsigned int v = w5[(size_t)perm[i] + half];
        s0 += __uint_as_float((v >> sh) << 16);
    }
    sc += (s0 + s1) + (s2 + s3);

    // softmax over the 10 active lanes of this 16-lane group
    float m = (c < 10) ? sc : -3.0e38f;
#pragma unroll
    for (int d = 1; d < 16; d <<= 1) m = fmaxf(m, __shfl_xor(m, d, 16));
    const float ex = (c < 10) ? __expf(sc - m) : 0.f;
    float sum = ex;
#pragma unroll
    for (int d = 1; d < 16; d <<= 1) sum += __shfl_xor(sum, d, 16);
    if (c < 10) out[(size_t)n * 10 + c] = ex / sum;
}

extern "C" void kernel_launch(void* const* d_in, const int* in_sizes, int n_in,
                              void* d_out, int out_size, void* d_ws, size_t ws_size,
                              hipStream_t stream)
{
    const float* O    = (const float*)d_in[0];
    const float* X    = (const float*)d_in[1];
    const float* R_a  = (const float*)d_in[2];
    const int* senders   = (const int*)d_in[3];
    const int* receivers = (const int*)d_in[4];
    const float* W_r  = (const float*)d_in[5];
    const float* b_r  = (const float*)d_in[6];
    const float* W_o  = (const float*)d_in[7];
    const float* b_o  = (const float*)d_in[8];
    const float* W_s  = (const float*)d_in[9];
    const float* b_s  = (const float*)d_in[10];
    float* out = (float*)d_out;
    char* ws = (char*)d_ws;

    float* A      = (float*)(ws + WS_A);
    int* count    = (int*)(ws + WS_COUNT);
    unsigned int* cursor = (unsigned int*)(ws + WS_CURSOR);
    int* off      = (int*)(ws + WS_OFF);
    int* cur      = (int*)(ws + WS_CUR);
    float* us     = (float*)(ws + WS_US);
    float* u01    = (float*)(ws + WS_U01);
    int* perm     = (int*)(ws + WS_PERM);
    unsigned int* w5 = (unsigned int*)(ws + WS_W5);

    // zero count histogram + cursor (adjacent) in one memset
    hipMemsetAsync(count, 0, (size_t)(200000 + 4 + 384), stream);

    precompute_A<<<10, 256, 0, stream>>>(W_r, b_r, W_o, b_o, W_s, b_s, A);

    count_kernel<<<(N_EDGES / 4 + 255) / 256, 256, 0, stream>>>(receivers, count);

    alloc_kernel<<<(N_NODES + 255) / 256, 256, 0, stream>>>(count, cursor, off, cur);

    node_u_kernel<<<(N_NODES * 10 + 255) / 256, 256, 0, stream>>>(O, X, A, us, u01);

    edge_w_kernel<<<(N_EDGES + 255) / 256, 256, 0, stream>>>(
        R_a, senders, receivers, us, A, cur, perm, w5);

    node_score_kernel<<<(N_NODES * 16 + 255) / 256, 256, 0, stream>>>(
        u01, off, count, perm, w5, out);
}

// Round 10
// 164.073 us; speedup vs baseline: 1.4239x; 1.1176x over previous
//
#include <hip/hip_runtime.h>

#define N_NODES 50000
#define N_EDGES 800000
// D_S=64, D_R=16, D_E=64, D_X=16, D_P=64, NUM_CLASSES=10
// W_r: [144,64]; W_o: [144,64]; W_s: [64,10] (all row-major)
//
// Linear refactor: scores[n] = u0[n] + deg_n*u1[n] + sum_{e->n} w_e
//   w_e  = u_s[s_e] + R_a[e]@A_R          (computed in EDGE order, streamed)
//   u_s[n] = O[n]@A_S ; u0[n] = O[n]@A_O + X[n]@A_X + c1 ; u1[n] = O[n]@A_dO + c0
// with Wc = W_o@W_s [144,10], Wc2 = Wc[80:144],
//   A_O = Wc[0:64], A_X = Wc[64:80], A_S = W_r[0:64]@Wc2,
//   A_R = W_r[128:144]@Wc2, A_dO = W_r[64:128]@Wc2,
//   c0 = b_r@Wc2, c1 = b_o@W_s + b_s.
//
// Atomic placement (lesson r9): the ONLY per-edge atomic lives in
// count_kernel, where its return value is the rank (fire-and-forget store).
// edge_w's critical path has NO atomic: pos = off[r] + rank[e] (plain loads),
// w bf16 written directly to sorted position. node_score reads w as a pure
// sequential stream — no gather, no perm.
//
// A-table layout in ws: [226][16] f32 (cols 10..15 zeroed):
//   rows 0..63 A_O | 64..79 A_X | 80..143 A_S | 144..159 A_R |
//   160..223 A_dO | 224 c0 | 225 c1

// ---------------------------------------------------------------------------
// Workspace layout (bytes) — end = 26,019,328 < 26,414,400 (proven in r3)
// ---------------------------------------------------------------------------
#define WS_A       ((size_t)0)          // 14,464 B
#define WS_COUNT   ((size_t)16384)      // 50000 i32 = 200,000 B
#define WS_CURSOR  ((size_t)216384)     // 1 u32 (zeroed with count memset)
#define WS_OFF     ((size_t)217088)     // 50000 i32 = 200,000 B
#define WS_RANK    ((size_t)417792)     // 800000 i32 = 3,200,000 B
#define WS_US      ((size_t)3618816)    // 50000*12 f32 = 2,400,000 B
#define WS_U01     ((size_t)6019072)    // 50000*20 f32 = 4,000,000 B
#define WS_WSORT   ((size_t)10019328)   // 800000*5 u32 = 16,000,000 B

__device__ __forceinline__ unsigned int f32_to_bf16_rne(float f) {
    unsigned int x = __float_as_uint(f);
    return (x + 0x7fffu + ((x >> 16) & 1u)) >> 16;
}

// ---------------------------------------------------------------------------
// Precompute folded weight table A — 10 blocks, redundant Wc2 in LDS
// ---------------------------------------------------------------------------
__global__ __launch_bounds__(256) void precompute_A(
    const float* __restrict__ W_r, const float* __restrict__ b_r,
    const float* __restrict__ W_o, const float* __restrict__ b_o,
    const float* __restrict__ W_s, const float* __restrict__ b_s,
    float* __restrict__ A)
{
    __shared__ float Wc2[640];  // Wc rows 80..143 (64 x 10)
    const int t = threadIdx.x;

    for (int idx = t; idx < 640; idx += 256) {
        const int row = 80 + idx / 10, c = idx % 10;
        float acc = 0.f;
        for (int j = 0; j < 64; ++j)
            acc = fmaf(W_o[row * 64 + j], W_s[j * 10 + c], acc);
        Wc2[idx] = acc;
    }
    __syncthreads();

    // work items: [0,1356) zero pads | [1356,2156) A_O/A_X | [2156,3596) A_S/A_R/A_dO
    //             [3596,3606) c0 | [3606,3616) c1
    for (int g = blockIdx.x * 256 + t; g < 3616; g += gridDim.x * 256) {
        if (g < 1356) {
            const int row = g / 6, c = 10 + g % 6;
            A[row * 16 + c] = 0.f;
        } else if (g < 2156) {
            const int i = g - 1356, row = i / 10, c = i % 10;
            float acc = 0.f;
            for (int j = 0; j < 64; ++j)
                acc = fmaf(W_o[row * 64 + j], W_s[j * 10 + c], acc);
            A[row * 16 + c] = acc;
        } else if (g < 3596) {
            const int i = g - 2156, k = i / 10, c = i % 10;
            const int wrow = (k < 64) ? k : (k < 80 ? 128 + (k - 64) : 64 + (k - 80));
            const int arow = (k < 64) ? 80 + k : (k < 80 ? 144 + (k - 64) : 160 + (k - 80));
            const float* src = W_r + (size_t)wrow * 64;
            float acc = 0.f;
            for (int m = 0; m < 64; ++m)
                acc = fmaf(src[m], Wc2[m * 10 + c], acc);
            A[arow * 16 + c] = acc;
        } else if (g < 3606) {
            const int c = g - 3596;
            float acc = 0.f;
            for (int m = 0; m < 64; ++m)
                acc = fmaf(b_r[m], Wc2[m * 10 + c], acc);
            A[224 * 16 + c] = acc;
        } else {
            const int c = g - 3606;
            float acc = b_s[c];
            for (int j = 0; j < 64; ++j)
                acc = fmaf(b_o[j], W_s[j * 10 + c], acc);
            A[225 * 16 + c] = acc;
        }
    }
}

// ---------------------------------------------------------------------------
// Per-node 10-vectors: u_s = O@A_S; u0 = O@A_O + X@A_X + c1; u1 = O@A_dO + c0
// ---------------------------------------------------------------------------
__global__ __launch_bounds__(256) void node_u_kernel(
    const float* __restrict__ O, const float* __restrict__ X,
    const float* __restrict__ A,
    float* __restrict__ us, float* __restrict__ u01)
{
    const int tid = blockIdx.x * 256 + threadIdx.x;
    if (tid >= N_NODES * 10) return;
    const int n = tid / 10;
    const int c = tid - n * 10;

    float vs = 0.f, v0 = 0.f, v1 = 0.f;
    const float* Orow = O + (size_t)n * 64;
#pragma unroll 8
    for (int k = 0; k < 64; ++k) {
        const float o = Orow[k];
        vs = fmaf(o, A[(size_t)(80 + k) * 16 + c], vs);
        v0 = fmaf(o, A[(size_t)k * 16 + c], v0);
        v1 = fmaf(o, A[(size_t)(160 + k) * 16 + c], v1);
    }
    const float* Xrow = X + (size_t)n * 16;
#pragma unroll
    for (int k = 0; k < 16; ++k)
        v0 = fmaf(Xrow[k], A[(size_t)(64 + k) * 16 + c], v0);

    us[(size_t)n * 12 + c] = vs;
    u01[(size_t)n * 20 + c]      = v0 + A[225 * 16 + c];  // + c1
    u01[(size_t)n * 20 + 10 + c] = v1 + A[224 * 16 + c];  // + c0
}

// ---------------------------------------------------------------------------
// Receiver histogram + rank: the atomic's return value IS the rank.
// 4 edges/thread; rank stores are fire-and-forget (no dependent work).
// ---------------------------------------------------------------------------
__global__ __launch_bounds__(256) void count_rank_kernel(
    const int* __restrict__ receivers, int* __restrict__ count,
    int* __restrict__ rank)
{
    const int t = blockIdx.x * 256 + threadIdx.x;
    if (t * 4 >= N_EDGES) return;
    const int4 r4 = reinterpret_cast<const int4*>(receivers)[t];
    int4 k4;
    k4.x = atomicAdd(count + r4.x, 1);
    k4.y = atomicAdd(count + r4.y, 1);
    k4.z = atomicAdd(count + r4.z, 1);
    k4.w = atomicAdd(count + r4.w, 1);
    reinterpret_cast<int4*>(rank)[t] = k4;
}

// ---------------------------------------------------------------------------
// Segment allocation, wave-aggregated: shfl prefix-sum, 1 atomic per wave.
// ---------------------------------------------------------------------------
__global__ __launch_bounds__(256) void alloc_kernel(
    const int* __restrict__ count, unsigned int* __restrict__ cursor,
    int* __restrict__ off)
{
    const int n = blockIdx.x * 256 + threadIdx.x;
    const int lane = threadIdx.x & 63;
    const int c = (n < N_NODES) ? count[n] : 0;

    int pre = c;
#pragma unroll
    for (int d = 1; d < 64; d <<= 1) {
        const int v = __shfl_up(pre, d);
        if (lane >= d) pre += v;
    }
    const int total = __shfl(pre, 63);
    int base = 0;
    if (lane == 63) base = (int)atomicAdd(cursor, (unsigned int)total);
    base = __shfl(base, 63);

    if (n < N_NODES) off[n] = base + pre - c;  // exclusive prefix
}

// ---------------------------------------------------------------------------
// Per-edge w_e = u_s[s_e] + R_a[e]@A_R -> bf16-packed, written directly to
// receiver-sorted slot pos = off[r] + rank[e]. NO atomic in this kernel.
// ---------------------------------------------------------------------------
__global__ __launch_bounds__(256) void edge_w_kernel(
    const float* __restrict__ R_a,
    const int* __restrict__ senders, const int* __restrict__ receivers,
    const int* __restrict__ rank, const int* __restrict__ off,
    const float* __restrict__ us, const float* __restrict__ A,
    unsigned int* __restrict__ wsort)   // [E][5] dwords, receiver-sorted
{
    const int e = blockIdx.x * blockDim.x + threadIdx.x;
    if (e >= N_EDGES) return;
    const int s = senders[e];
    const int r = receivers[e];
    const int pos = off[r] + rank[e];   // plain loads — no atomic

    // u_s[s]: 48 B gather from L2-resident 2.4 MB table
    const float4* U = reinterpret_cast<const float4*>(us + (size_t)s * 12);
    const float4 ua = U[0];
    const float4 ub = U[1];
    const float4 uc = U[2];
    float a[10] = {ua.x, ua.y, ua.z, ua.w, ub.x, ub.y, ub.z, ub.w, uc.x, uc.y};

    // R_a[e] @ A_R (A rows 144..159) — R_a streamed coalesced
    const float4* Rv = reinterpret_cast<const float4*>(R_a + (size_t)e * 16);
#pragma unroll
    for (int kc = 0; kc < 4; ++kc) {
        const float4 b4 = Rv[kc];
        const float* A0 = A + (size_t)(144 + kc * 4) * 16;
#pragma unroll
        for (int c = 0; c < 10; ++c) a[c] = fmaf(b4.x, A0[c], a[c]);
#pragma unroll
        for (int c = 0; c < 10; ++c) a[c] = fmaf(b4.y, A0[16 + c], a[c]);
#pragma unroll
        for (int c = 0; c < 10; ++c) a[c] = fmaf(b4.z, A0[32 + c], a[c]);
#pragma unroll
        for (int c = 0; c < 10; ++c) a[c] = fmaf(b4.w, A0[48 + c], a[c]);
    }

    unsigned int* wp = wsort + (size_t)pos * 5;
    wp[0] = f32_to_bf16_rne(a[0]) | (f32_to_bf16_rne(a[1]) << 16);
    wp[1] = f32_to_bf16_rne(a[2]) | (f32_to_bf16_rne(a[3]) << 16);
    wp[2] = f32_to_bf16_rne(a[4]) | (f32_to_bf16_rne(a[5]) << 16);
    wp[3] = f32_to_bf16_rne(a[6]) | (f32_to_bf16_rne(a[7]) << 16);
    wp[4] = f32_to_bf16_rne(a[8]) | (f32_to_bf16_rne(a[9]) << 16);
}

// ---------------------------------------------------------------------------
// Node scores: thread = (node, class-slot c<16). w read as a PURE SEQUENTIAL
// stream (receiver-sorted). 4-deep unroll, 4 accumulators. 16-lane softmax.
// ---------------------------------------------------------------------------
__global__ __launch_bounds__(256) void node_score_kernel(
    const float* __restrict__ u01,
    const int* __restrict__ off, const int* __restrict__ count,
    const unsigned int* __restrict__ w,   // [E][5] dwords, receiver-sorted
    float* __restrict__ out)
{
    const int tid = blockIdx.x * 256 + threadIdx.x;
    const int n = tid >> 4;
    const int c = tid & 15;
    if (n >= N_NODES) return;

    const int cc = (c < 10) ? c : 0;  // safe column for idle lanes
    const int half = cc >> 1;
    const int sh = (cc & 1) * 16;

    const int beg = off[n];
    const int dge = count[n];
    const int end = beg + dge;
    float sc = u01[(size_t)n * 20 + cc] + (float)dge * u01[(size_t)n * 20 + 10 + cc];

    float s0 = 0.f, s1 = 0.f, s2 = 0.f, s3 = 0.f;
    int i = beg;
    for (; i + 3 < end; i += 4) {
        const unsigned int v0 = w[(size_t)(i + 0) * 5 + half];
        const unsigned int v1 = w[(size_t)(i + 1) * 5 + half];
        const unsigned int v2 = w[(size_t)(i + 2) * 5 + half];
        const unsigned int v3 = w[(size_t)(i + 3) * 5 + half];
        s0 += __uint_as_float((v0 >> sh) << 16);
        s1 += __uint_as_float((v1 >> sh) << 16);
        s2 += __uint_as_float((v2 >> sh) << 16);
        s3 += __uint_as_float((v3 >> sh) << 16);
    }
    for (; i < end; ++i) {
        const unsigned int v = w[(size_t)i * 5 + half];
        s0 += __uint_as_float((v >> sh) << 16);
    }
    sc += (s0 + s1) + (s2 + s3);

    // softmax over the 10 active lanes of this 16-lane group
    float m = (c < 10) ? sc : -3.0e38f;
#pragma unroll
    for (int d = 1; d < 16; d <<= 1) m = fmaxf(m, __shfl_xor(m, d, 16));
    const float ex = (c < 10) ? __expf(sc - m) : 0.f;
    float sum = ex;
#pragma unroll
    for (int d = 1; d < 16; d <<= 1) sum += __shfl_xor(sum, d, 16);
    if (c < 10) out[(size_t)n * 10 + c] = ex / sum;
}

extern "C" void kernel_launch(void* const* d_in, const int* in_sizes, int n_in,
                              void* d_out, int out_size, void* d_ws, size_t ws_size,
                              hipStream_t stream)
{
    const float* O    = (const float*)d_in[0];
    const float* X    = (const float*)d_in[1];
    const float* R_a  = (const float*)d_in[2];
    const int* senders   = (const int*)d_in[3];
    const int* receivers = (const int*)d_in[4];
    const float* W_r  = (const float*)d_in[5];
    const float* b_r  = (const float*)d_in[6];
    const float* W_o  = (const float*)d_in[7];
    const float* b_o  = (const float*)d_in[8];
    const float* W_s  = (const float*)d_in[9];
    const float* b_s  = (const float*)d_in[10];
    float* out = (float*)d_out;
    char* ws = (char*)d_ws;

    float* A      = (float*)(ws + WS_A);
    int* count    = (int*)(ws + WS_COUNT);
    unsigned int* cursor = (unsigned int*)(ws + WS_CURSOR);
    int* off      = (int*)(ws + WS_OFF);
    int* rank     = (int*)(ws + WS_RANK);
    float* us     = (float*)(ws + WS_US);
    float* u01    = (float*)(ws + WS_U01);
    unsigned int* wsort = (unsigned int*)(ws + WS_WSORT);

    // zero count histogram + cursor (adjacent) in one memset
    hipMemsetAsync(count, 0, (size_t)(200000 + 4 + 384), stream);

    precompute_A<<<10, 256, 0, stream>>>(W_r, b_r, W_o, b_o, W_s, b_s, A);

    count_rank_kernel<<<(N_EDGES / 4 + 255) / 256, 256, 0, stream>>>(
        receivers, count, rank);

    alloc_kernel<<<(N_NODES + 255) / 256, 256, 0, stream>>>(count, cursor, off);

    node_u_kernel<<<(N_NODES * 10 + 255) / 256, 256, 0, stream>>>(O, X, A, us, u01);

    edge_w_kernel<<<(N_EDGES + 255) / 256, 256, 0, stream>>>(
        R_a, senders, receivers, rank, off, us, A, wsort);

    node_score_kernel<<<(N_NODES * 16 + 255) / 256, 256, 0, stream>>>(
        u01, off, count, wsort, out);
}

// Round 11
// 125.716 us; speedup vs baseline: 1.8583x; 1.3051x over previous
//
#include <hip/hip_runtime.h>

#define N_NODES 50000
#define N_EDGES 800000
// D_S=64, D_R=16, D_E=64, D_X=16, D_P=64, NUM_CLASSES=10
// W_r: [144,64]; W_o: [144,64]; W_s: [64,10] (all row-major)
//
// Linear refactor: scores[n] = u0[n] + deg_n*u1[n] + sum_{e->n} w_e
//   w_e  = u_s[s_e] + R_a[e]@A_R          (computed in EDGE order, streamed)
//   u_s[n] = O[n]@A_S ; u0[n] = O[n]@A_O + X[n]@A_X + c1 ; u1[n] = O[n]@A_dO + c0
// with Wc = W_o@W_s [144,10], Wc2 = Wc[80:144],
//   A_O = Wc[0:64], A_X = Wc[64:80], A_S = W_r[0:64]@Wc2,
//   A_R = W_r[128:144]@Wc2, A_dO = W_r[64:128]@Wc2,
//   c0 = b_r@Wc2, c1 = b_o@W_s + b_s.
//
// Atomic placement (lesson r9): the ONLY per-edge atomic lives in
// count_rank_kernel, where its return value is the rank. edge_w has no
// atomic: pos = off[r] + rank[e], w bf16 written directly to sorted slot.
// node_score reads w as a pure sequential stream.
//
// node_u lesson (r10): table loads must come from LDS, not per-lane global
// scalar loads — 256 vector-memory ops/thread was issue-bound at 5% VALU.
//
// A-table layout in ws: [226][16] f32 (cols 10..15 zeroed):
//   rows 0..63 A_O | 64..79 A_X | 80..143 A_S | 144..159 A_R |
//   160..223 A_dO | 224 c0 | 225 c1

// ---------------------------------------------------------------------------
// Workspace layout (bytes) — end = 26,019,328 < 26,414,400 (proven in r3)
// ---------------------------------------------------------------------------
#define WS_A       ((size_t)0)          // 14,464 B
#define WS_COUNT   ((size_t)16384)      // 50000 i32 = 200,000 B
#define WS_CURSOR  ((size_t)216384)     // 1 u32 (zeroed with count memset)
#define WS_OFF     ((size_t)217088)     // 50000 i32 = 200,000 B
#define WS_RANK    ((size_t)417792)     // 800000 i32 = 3,200,000 B
#define WS_US      ((size_t)3618816)    // 50000*12 f32 = 2,400,000 B
#define WS_U01     ((size_t)6019072)    // 50000*20 f32 = 4,000,000 B
#define WS_WSORT   ((size_t)10019328)   // 800000*5 u32 = 16,000,000 B

__device__ __forceinline__ unsigned int f32_to_bf16_rne(float f) {
    unsigned int x = __float_as_uint(f);
    return (x + 0x7fffu + ((x >> 16) & 1u)) >> 16;
}

// ---------------------------------------------------------------------------
// Precompute folded weight table A — 10 blocks, redundant Wc2 in LDS
// ---------------------------------------------------------------------------
__global__ __launch_bounds__(256) void precompute_A(
    const float* __restrict__ W_r, const float* __restrict__ b_r,
    const float* __restrict__ W_o, const float* __restrict__ b_o,
    const float* __restrict__ W_s, const float* __restrict__ b_s,
    float* __restrict__ A)
{
    __shared__ float Wc2[640];  // Wc rows 80..143 (64 x 10)
    const int t = threadIdx.x;

    for (int idx = t; idx < 640; idx += 256) {
        const int row = 80 + idx / 10, c = idx % 10;
        float acc = 0.f;
        for (int j = 0; j < 64; ++j)
            acc = fmaf(W_o[row * 64 + j], W_s[j * 10 + c], acc);
        Wc2[idx] = acc;
    }
    __syncthreads();

    // work items: [0,1356) zero pads | [1356,2156) A_O/A_X | [2156,3596) A_S/A_R/A_dO
    //             [3596,3606) c0 | [3606,3616) c1
    for (int g = blockIdx.x * 256 + t; g < 3616; g += gridDim.x * 256) {
        if (g < 1356) {
            const int row = g / 6, c = 10 + g % 6;
            A[row * 16 + c] = 0.f;
        } else if (g < 2156) {
            const int i = g - 1356, row = i / 10, c = i % 10;
            float acc = 0.f;
            for (int j = 0; j < 64; ++j)
                acc = fmaf(W_o[row * 64 + j], W_s[j * 10 + c], acc);
            A[row * 16 + c] = acc;
        } else if (g < 3596) {
            const int i = g - 2156, k = i / 10, c = i % 10;
            const int wrow = (k < 64) ? k : (k < 80 ? 128 + (k - 64) : 64 + (k - 80));
            const int arow = (k < 64) ? 80 + k : (k < 80 ? 144 + (k - 64) : 160 + (k - 80));
            const float* src = W_r + (size_t)wrow * 64;
            float acc = 0.f;
            for (int m = 0; m < 64; ++m)
                acc = fmaf(src[m], Wc2[m * 10 + c], acc);
            A[arow * 16 + c] = acc;
        } else if (g < 3606) {
            const int c = g - 3596;
            float acc = 0.f;
            for (int m = 0; m < 64; ++m)
                acc = fmaf(b_r[m], Wc2[m * 10 + c], acc);
            A[224 * 16 + c] = acc;
        } else {
            const int c = g - 3606;
            float acc = b_s[c];
            for (int j = 0; j < 64; ++j)
                acc = fmaf(b_o[j], W_s[j * 10 + c], acc);
            A[225 * 16 + c] = acc;
        }
    }
}

// ---------------------------------------------------------------------------
// Per-node 10-vectors, rebuilt (r10 lesson): thread = (node, class-PAIR),
// A staged in LDS as float2 pairs, O/X read as float4. 250K threads.
// ---------------------------------------------------------------------------
__global__ __launch_bounds__(256) void node_u_kernel(
    const float* __restrict__ O, const float* __restrict__ X,
    const float* __restrict__ A,
    float* __restrict__ us, float* __restrict__ u01)
{
    __shared__ float2 lA[226 * 5];  // lA[row*5+cp] = (A[row][2cp], A[row][2cp+1])
    const int t = threadIdx.x;
    for (int i = t; i < 226 * 5; i += 256) {
        const int row = i / 5, cp = i - row * 5;
        lA[i] = *reinterpret_cast<const float2*>(A + (size_t)row * 16 + 2 * cp);
    }
    __syncthreads();

    const int tid = blockIdx.x * 256 + t;
    if (tid >= N_NODES * 5) return;
    const int n = tid / 5;
    const int cp = tid - n * 5;

    float vs0 = 0.f, vs1 = 0.f, v00 = 0.f, v01 = 0.f, v10 = 0.f, v11 = 0.f;

    const float4* Ov = reinterpret_cast<const float4*>(O + (size_t)n * 64);
#pragma unroll
    for (int kc = 0; kc < 16; ++kc) {
        const float4 o4 = Ov[kc];
#pragma unroll
        for (int j = 0; j < 4; ++j) {
            const float ov = (j == 0) ? o4.x : (j == 1) ? o4.y : (j == 2) ? o4.z : o4.w;
            const int k = kc * 4 + j;
            const float2 aO = lA[k * 5 + cp];            // A_O row k
            const float2 aS = lA[(80 + k) * 5 + cp];     // A_S row k
            const float2 aD = lA[(160 + k) * 5 + cp];    // A_dO row k
            v00 = fmaf(ov, aO.x, v00); v01 = fmaf(ov, aO.y, v01);
            vs0 = fmaf(ov, aS.x, vs0); vs1 = fmaf(ov, aS.y, vs1);
            v10 = fmaf(ov, aD.x, v10); v11 = fmaf(ov, aD.y, v11);
        }
    }
    const float4* Xv = reinterpret_cast<const float4*>(X + (size_t)n * 16);
#pragma unroll
    for (int kc = 0; kc < 4; ++kc) {
        const float4 x4 = Xv[kc];
#pragma unroll
        for (int j = 0; j < 4; ++j) {
            const float xv = (j == 0) ? x4.x : (j == 1) ? x4.y : (j == 2) ? x4.z : x4.w;
            const int k = 64 + kc * 4 + j;
            const float2 aX = lA[k * 5 + cp];            // A_X row
            v00 = fmaf(xv, aX.x, v00); v01 = fmaf(xv, aX.y, v01);
        }
    }

    const float2 c0 = lA[224 * 5 + cp];
    const float2 c1 = lA[225 * 5 + cp];
    *reinterpret_cast<float2*>(us + (size_t)n * 12 + 2 * cp) = make_float2(vs0, vs1);
    *reinterpret_cast<float2*>(u01 + (size_t)n * 20 + 2 * cp) =
        make_float2(v00 + c1.x, v01 + c1.y);
    *reinterpret_cast<float2*>(u01 + (size_t)n * 20 + 10 + 2 * cp) =
        make_float2(v10 + c0.x, v11 + c0.y);
}

// ---------------------------------------------------------------------------
// Receiver histogram + rank: the atomic's return value IS the rank.
// ---------------------------------------------------------------------------
__global__ __launch_bounds__(256) void count_rank_kernel(
    const int* __restrict__ receivers, int* __restrict__ count,
    int* __restrict__ rank)
{
    const int t = blockIdx.x * 256 + threadIdx.x;
    if (t * 4 >= N_EDGES) return;
    const int4 r4 = reinterpret_cast<const int4*>(receivers)[t];
    int4 k4;
    k4.x = atomicAdd(count + r4.x, 1);
    k4.y = atomicAdd(count + r4.y, 1);
    k4.z = atomicAdd(count + r4.z, 1);
    k4.w = atomicAdd(count + r4.w, 1);
    reinterpret_cast<int4*>(rank)[t] = k4;
}

// ---------------------------------------------------------------------------
// Segment allocation, wave-aggregated: shfl prefix-sum, 1 atomic per wave.
// ---------------------------------------------------------------------------
__global__ __launch_bounds__(256) void alloc_kernel(
    const int* __restrict__ count, unsigned int* __restrict__ cursor,
    int* __restrict__ off)
{
    const int n = blockIdx.x * 256 + threadIdx.x;
    const int lane = threadIdx.x & 63;
    const int c = (n < N_NODES) ? count[n] : 0;

    int pre = c;
#pragma unroll
    for (int d = 1; d < 64; d <<= 1) {
        const int v = __shfl_up(pre, d);
        if (lane >= d) pre += v;
    }
    const int total = __shfl(pre, 63);
    int base = 0;
    if (lane == 63) base = (int)atomicAdd(cursor, (unsigned int)total);
    base = __shfl(base, 63);

    if (n < N_NODES) off[n] = base + pre - c;  // exclusive prefix
}

// ---------------------------------------------------------------------------
// Per-edge w_e = u_s[s_e] + R_a[e]@A_R -> bf16-packed, written directly to
// receiver-sorted slot pos = off[r] + rank[e]. NO atomic in this kernel.
// ---------------------------------------------------------------------------
__global__ __launch_bounds__(256) void edge_w_kernel(
    const float* __restrict__ R_a,
    const int* __restrict__ senders, const int* __restrict__ receivers,
    const int* __restrict__ rank, const int* __restrict__ off,
    const float* __restrict__ us, const float* __restrict__ A,
    unsigned int* __restrict__ wsort)   // [E][5] dwords, receiver-sorted
{
    const int e = blockIdx.x * blockDim.x + threadIdx.x;
    if (e >= N_EDGES) return;
    const int s = senders[e];
    const int r = receivers[e];
    const int pos = off[r] + rank[e];   // plain loads — no atomic

    // u_s[s]: 48 B gather from L2-resident 2.4 MB table
    const float4* U = reinterpret_cast<const float4*>(us + (size_t)s * 12);
    const float4 ua = U[0];
    const float4 ub = U[1];
    const float4 uc = U[2];
    float a[10] = {ua.x, ua.y, ua.z, ua.w, ub.x, ub.y, ub.z, ub.w, uc.x, uc.y};

    // R_a[e] @ A_R (A rows 144..159) — R_a streamed coalesced
    const float4* Rv = reinterpret_cast<const float4*>(R_a + (size_t)e * 16);
#pragma unroll
    for (int kc = 0; kc < 4; ++kc) {
        const float4 b4 = Rv[kc];
        const float* A0 = A + (size_t)(144 + kc * 4) * 16;
#pragma unroll
        for (int c = 0; c < 10; ++c) a[c] = fmaf(b4.x, A0[c], a[c]);
#pragma unroll
        for (int c = 0; c < 10; ++c) a[c] = fmaf(b4.y, A0[16 + c], a[c]);
#pragma unroll
        for (int c = 0; c < 10; ++c) a[c] = fmaf(b4.z, A0[32 + c], a[c]);
#pragma unroll
        for (int c = 0; c < 10; ++c) a[c] = fmaf(b4.w, A0[48 + c], a[c]);
    }

    unsigned int* wp = wsort + (size_t)pos * 5;
    wp[0] = f32_to_bf16_rne(a[0]) | (f32_to_bf16_rne(a[1]) << 16);
    wp[1] = f32_to_bf16_rne(a[2]) | (f32_to_bf16_rne(a[3]) << 16);
    wp[2] = f32_to_bf16_rne(a[4]) | (f32_to_bf16_rne(a[5]) << 16);
    wp[3] = f32_to_bf16_rne(a[6]) | (f32_to_bf16_rne(a[7]) << 16);
    wp[4] = f32_to_bf16_rne(a[8]) | (f32_to_bf16_rne(a[9]) << 16);
}

// ---------------------------------------------------------------------------
// Node scores: thread = (node, class-slot c<16). w read as a PURE SEQUENTIAL
// stream (receiver-sorted). 4-deep unroll, 4 accumulators. 16-lane softmax.
// ---------------------------------------------------------------------------
__global__ __launch_bounds__(256) void node_score_kernel(
    const float* __restrict__ u01,
    const int* __restrict__ off, const int* __restrict__ count,
    const unsigned int* __restrict__ w,   // [E][5] dwords, receiver-sorted
    float* __restrict__ out)
{
    const int tid = blockIdx.x * 256 + threadIdx.x;
    const int n = tid >> 4;
    const int c = tid & 15;
    if (n >= N_NODES) return;

    const int cc = (c < 10) ? c : 0;  // safe column for idle lanes
    const int half = cc >> 1;
    const int sh = (cc & 1) * 16;

    const int beg = off[n];
    const int dge = count[n];
    const int end = beg + dge;
    float sc = u01[(size_t)n * 20 + cc] + (float)dge * u01[(size_t)n * 20 + 10 + cc];

    float s0 = 0.f, s1 = 0.f, s2 = 0.f, s3 = 0.f;
    int i = beg;
    for (; i + 3 < end; i += 4) {
        const unsigned int v0 = w[(size_t)(i + 0) * 5 + half];
        const unsigned int v1 = w[(size_t)(i + 1) * 5 + half];
        const unsigned int v2 = w[(size_t)(i + 2) * 5 + half];
        const unsigned int v3 = w[(size_t)(i + 3) * 5 + half];
        s0 += __uint_as_float((v0 >> sh) << 16);
        s1 += __uint_as_float((v1 >> sh) << 16);
        s2 += __uint_as_float((v2 >> sh) << 16);
        s3 += __uint_as_float((v3 >> sh) << 16);
    }
    for (; i < end; ++i) {
        const unsigned int v = w[(size_t)i * 5 + half];
        s0 += __uint_as_float((v >> sh) << 16);
    }
    sc += (s0 + s1) + (s2 + s3);

    // softmax over the 10 active lanes of this 16-lane group
    float m = (c < 10) ? sc : -3.0e38f;
#pragma unroll
    for (int d = 1; d < 16; d <<= 1) m = fmaxf(m, __shfl_xor(m, d, 16));
    const float ex = (c < 10) ? __expf(sc - m) : 0.f;
    float sum = ex;
#pragma unroll
    for (int d = 1; d < 16; d <<= 1) sum += __shfl_xor(sum, d, 16);
    if (c < 10) out[(size_t)n * 10 + c] = ex / sum;
}

extern "C" void kernel_launch(void* const* d_in, const int* in_sizes, int n_in,
                              void* d_out, int out_size, void* d_ws, size_t ws_size,
                              hipStream_t stream)
{
    const float* O    = (const float*)d_in[0];
    const float* X    = (const float*)d_in[1];
    const float* R_a  = (const float*)d_in[2];
    const int* senders   = (const int*)d_in[3];
    const int* receivers = (const int*)d_in[4];
    const float* W_r  = (const float*)d_in[5];
    const float* b_r  = (const float*)d_in[6];
    const float* W_o  = (const float*)d_in[7];
    const float* b_o  = (const float*)d_in[8];
    const float* W_s  = (const float*)d_in[9];
    const float* b_s  = (const float*)d_in[10];
    float* out = (float*)d_out;
    char* ws = (char*)d_ws;

    float* A      = (float*)(ws + WS_A);
    int* count    = (int*)(ws + WS_COUNT);
    unsigned int* cursor = (unsigned int*)(ws + WS_CURSOR);
    int* off      = (int*)(ws + WS_OFF);
    int* rank     = (int*)(ws + WS_RANK);
    float* us     = (float*)(ws + WS_US);
    float* u01    = (float*)(ws + WS_U01);
    unsigned int* wsort = (unsigned int*)(ws + WS_WSORT);

    // zero count histogram + cursor (adjacent) in one memset
    hipMemsetAsync(count, 0, (size_t)(200000 + 4 + 384), stream);

    precompute_A<<<10, 256, 0, stream>>>(W_r, b_r, W_o, b_o, W_s, b_s, A);

    count_rank_kernel<<<(N_EDGES / 4 + 255) / 256, 256, 0, stream>>>(
        receivers, count, rank);

    alloc_kernel<<<(N_NODES + 255) / 256, 256, 0, stream>>>(count, cursor, off);

    node_u_kernel<<<(N_NODES * 5 + 255) / 256, 256, 0, stream>>>(O, X, A, us, u01);

    edge_w_kernel<<<(N_EDGES + 255) / 256, 256, 0, stream>>>(
        R_a, senders, receivers, rank, off, us, A, wsort);

    node_score_kernel<<<(N_NODES * 16 + 255) / 256, 256, 0, stream>>>(
        u01, off, count, wsort, out);
}